// Round 1
// baseline (99.749 us; speedup 1.0000x reference)
//
#include <hip/hip_runtime.h>
#include <math.h>

#define BB 64
#define TT 1024
#define DD 256
#define BT (BB*TT)
#define SS 16            // token-chunks per batch for kernel A
#define TPC (TT/SS)      // 64 tokens per chunk

// ---- workspace layout (in floats) ----
#define PA_OFF   0                      // [BB*SS][DD] partial token sums
#define MB_OFF   (PA_OFF + BB*SS*DD)    // [BB][DD] per-batch centroids
#define MEAN_OFF (MB_OFF + BB*DD)       // [DD] final mean
#define W_OFF    (MEAN_OFF + DD)        // [DD] mean + beta
#define SC_OFF   (W_OFF + DD)           // scalars: [0]=scale, [1]=invdenom
#define XY_OFF   (SC_OFF + 16)          // [BT] per-token <mean,x>_L
#define DP_OFF   (XY_OFF + BT)          // [1024] dist partial sums
#define WS_FLOATS (DP_OFF + 1024)

__device__ __forceinline__ float block_reduce_256(float v) {
    __shared__ float sh[4];
    #pragma unroll
    for (int o = 32; o; o >>= 1) v += __shfl_xor(v, o, 64);
    int lane = threadIdx.x & 63, w = threadIdx.x >> 6;
    if (lane == 0) sh[w] = v;
    __syncthreads();
    float r = sh[0] + sh[1] + sh[2] + sh[3];
    __syncthreads();
    return r;
}

// ---- Kernel A: per (batch, chunk) token sums ----
__global__ void kA(const float* __restrict__ x, float* __restrict__ ws) {
    int chunk = blockIdx.x;          // 0 .. BB*SS-1
    int d = threadIdx.x;             // 0 .. 255
    int b = chunk / SS, s = chunk % SS;
    const float* xp = x + (size_t)(b*TT + s*TPC) * DD + d;
    float sum = 0.f;
    #pragma unroll 8
    for (int t = 0; t < TPC; ++t) sum += xp[(size_t)t * DD];
    ws[PA_OFF + (size_t)chunk * DD + d] = sum;
}

// ---- Kernel B1: per-batch centroid normalize (grid = BB) ----
__global__ void kB1(float* __restrict__ ws) {
    int b = blockIdx.x, d = threadIdx.x;
    float m = 0.f;
    #pragma unroll
    for (int s = 0; s < SS; ++s) m += ws[PA_OFF + (size_t)(b*SS + s) * DD + d];
    m *= (1.0f / TT);
    float dot = block_reduce_256(d == 0 ? -m*m : m*m);   // l_inner(m,m)
    float q = fmaxf(-dot, 1e-8f);
    ws[MB_OFF + (size_t)b * DD + d] = m / sqrtf(q);
}

// ---- Kernel B2: batch centroid + precompute w, invdenom (1 block) ----
__global__ void kB2(const float* __restrict__ beta, float* __restrict__ ws) {
    int d = threadIdx.x;
    float a = 0.f;
    #pragma unroll 8
    for (int b = 0; b < BB; ++b) a += ws[MB_OFF + (size_t)b * DD + d];
    a *= (1.0f / BB);
    float dot = block_reduce_256(d == 0 ? -a*a : a*a);
    float mean = a / sqrtf(fmaxf(-dot, 1e-8f));
    ws[MEAN_OFF + d] = mean;
    float bt = beta[d];
    ws[W_OFF + d] = mean + bt;
    float mb = block_reduce_256(d == 0 ? -mean*bt : mean*bt); // l_inner(mean,beta)
    if (d == 0) ws[SC_OFF + 1] = 1.0f / (1.0f - mb);
}

// ---- Kernel C: per-token xy + distance partial sums (wave per token) ----
__global__ void kC(const float* __restrict__ x, float* __restrict__ ws) {
    int tid = threadIdx.x, lane = tid & 63, wv = tid >> 6;
    int gw = blockIdx.x * 4 + wv;
    int nw = gridDim.x * 4;
    float4 m4 = ((const float4*)(ws + MEAN_OFF))[lane];
    float sgn0 = (lane == 0) ? -1.f : 1.f;
    float lsum = 0.f;
    for (int tok = gw; tok < BT; tok += nw) {
        float4 x4 = ((const float4*)(x + (size_t)tok * DD))[lane];
        float p = sgn0 * m4.x * x4.x + m4.y * x4.y + m4.z * x4.z + m4.w * x4.w;
        #pragma unroll
        for (int o = 32; o; o >>= 1) p += __shfl_xor(p, o, 64);
        if (lane == 0) ws[XY_OFF + tok] = p;
        float arg = fmaxf(-p, 1.0f + 1e-7f);
        float dd = acoshf(arg);
        lsum += fmaxf(dd * dd, 1e-8f);
    }
    __shared__ float sh[4];
    if (lane == 0) sh[wv] = lsum;
    __syncthreads();
    if (tid == 0) ws[DP_OFF + blockIdx.x] = sh[0] + sh[1] + sh[2] + sh[3];
}

// ---- Kernel D: final variance -> scale (1 block) ----
__global__ void kD(const float* __restrict__ gamma, float* __restrict__ ws) {
    int tid = threadIdx.x;
    float s = 0.f;
    #pragma unroll
    for (int i = tid; i < 1024; i += 256) s += ws[DP_OFF + i];
    float tot = block_reduce_256(s);
    if (tid == 0) {
        float var = sqrtf(tot / (float)BT);
        ws[SC_OFF + 0] = gamma[0] / (var + 1e-5f);
    }
}

// ---- Kernel E: output pass (wave per token) ----
__global__ void kE(const float* __restrict__ x, const float* __restrict__ beta,
                   const float* __restrict__ ws, float* __restrict__ out) {
    int tid = threadIdx.x, lane = tid & 63, wv = tid >> 6;
    int gw = blockIdx.x * 4 + wv;
    int nw = gridDim.x * 4;
    float4 m4 = ((const float4*)(ws + MEAN_OFF))[lane];
    float4 b4 = ((const float4*)beta)[lane];
    float4 w4 = ((const float4*)(ws + W_OFF))[lane];
    float scale  = ws[SC_OFF + 0];
    float invden = ws[SC_OFF + 1];
    float sgn0 = (lane == 0) ? -1.f : 1.f;
    for (int tok = gw; tok < BT; tok += nw) {
        float4 x4 = ((const float4*)(x + (size_t)tok * DD))[lane];
        float xy = ws[XY_OFF + tok];
        float dd = acoshf(fmaxf(-xy, 1.0f + 1e-7f));
        // u = x + xy*mean
        float4 u;
        u.x = x4.x + xy * m4.x;
        u.y = x4.y + xy * m4.y;
        u.z = x4.z + xy * m4.z;
        u.w = x4.w + xy * m4.w;
        float un2 = sgn0 * u.x * u.x + u.y * u.y + u.z * u.z + u.w * u.w;
        #pragma unroll
        for (int o = 32; o; o >>= 1) un2 += __shfl_xor(un2, o, 64);
        float un = sqrtf(fmaxf(un2, 1e-8f));
        float f1 = dd / un * scale;          // logmap scale * gamma/(var+eps)
        float4 v;
        v.x = u.x * f1; v.y = u.y * f1; v.z = u.z * f1; v.w = u.w * f1;
        // fused: Euclidean norm^2 of v  and  l_inner(beta, v)
        float en2 = v.x * v.x + v.y * v.y + v.z * v.z + v.w * v.w;
        float bv  = sgn0 * b4.x * v.x + b4.y * v.y + b4.z * v.z + b4.w * v.w;
        #pragma unroll
        for (int o = 32; o; o >>= 1) {
            en2 += __shfl_xor(en2, o, 64);
            bv  += __shfl_xor(bv,  o, 64);
        }
        float n = sqrtf(en2);
        float factor = fminf(1.0f, 32.0f / fmaxf(n, 1e-8f));
        float coeff = bv * factor * invden;  // l_inner(beta, v*factor) / (1 - l_inner(mean,beta))
        float4 v2;
        v2.x = v.x * factor + coeff * w4.x;
        v2.y = v.y * factor + coeff * w4.y;
        v2.z = v.z * factor + coeff * w4.z;
        v2.w = v.w * factor + coeff * w4.w;
        float vn2 = sgn0 * v2.x * v2.x + v2.y * v2.y + v2.z * v2.z + v2.w * v2.w;
        #pragma unroll
        for (int o = 32; o; o >>= 1) vn2 += __shfl_xor(vn2, o, 64);
        float vn = sqrtf(fmaxf(vn2, 1e-8f));
        float shv = sinhf(vn) / vn;
        float chv = coshf(vn);
        float4 o4;
        o4.x = chv * b4.x + shv * v2.x;
        o4.y = chv * b4.y + shv * v2.y;
        o4.z = chv * b4.z + shv * v2.z;
        o4.w = chv * b4.w + shv * v2.w;
        ((float4*)(out + (size_t)tok * DD))[lane] = o4;
    }
}

extern "C" void kernel_launch(void* const* d_in, const int* in_sizes, int n_in,
                              void* d_out, int out_size, void* d_ws, size_t ws_size,
                              hipStream_t stream) {
    const float* x     = (const float*)d_in[0];
    const float* beta  = (const float*)d_in[1];
    const float* gamma = (const float*)d_in[2];
    float* out = (float*)d_out;
    float* ws  = (float*)d_ws;

    kA <<<BB*SS, 256, 0, stream>>>(x, ws);
    kB1<<<BB,    256, 0, stream>>>(ws);
    kB2<<<1,     256, 0, stream>>>(beta, ws);
    kC <<<1024,  256, 0, stream>>>(x, ws);
    kD <<<1,     256, 0, stream>>>(gamma, ws);
    kE <<<1024,  256, 0, stream>>>(x, beta, ws, out);
}

// Round 2
// 79.333 us; speedup vs baseline: 1.2573x; 1.2573x over previous
//
#include <hip/hip_runtime.h>
#include <math.h>

#define BB 64
#define TT 1024
#define DD 256
#define BT (BB*TT)
#define SS 16            // token-chunks per batch for kernel A
#define TPC (TT/SS)      // 64 tokens per chunk

// ---- workspace layout (in floats) ----
#define PA_OFF   0                       // [1024][256] partial token sums (kA->kB); aliased by ABC after kB
#define ABC_OFF  PA_OFF                  // [BT][4] per-token A,B,C (kS->kE)  -- aliases PA (PA dead after kB)
#define MEAN_OFF (PA_OFF + BB*SS*DD)     // [256] final mean
#define SC_OFF   (MEAN_OFF + DD)         // scalars: [1]=invden, [2]=mb, [3]=ww, [4]=mean0
#define SCAL_OFF (SC_OFF + 16)           // [BT][4] per-token (xy, by, y0, 0)
#define DP_OFF   (SCAL_OFF + BT*4)       // [2048] dist^2 partial sums
#define WS_FLOATS (DP_OFF + 2048)

__device__ __forceinline__ float block_reduce_256(float v) {
    __shared__ float sh[4];
    #pragma unroll
    for (int o = 32; o; o >>= 1) v += __shfl_xor(v, o, 64);
    int lane = threadIdx.x & 63, w = threadIdx.x >> 6;
    if (lane == 0) sh[w] = v;
    __syncthreads();
    float r = sh[0] + sh[1] + sh[2] + sh[3];
    __syncthreads();
    return r;
}

// ---- Kernel A: per (batch, chunk) token sums ----
__global__ void kA(const float* __restrict__ x, float* __restrict__ ws) {
    int chunk = blockIdx.x;          // 0 .. 1023
    int d = threadIdx.x;             // 0 .. 255
    int b = chunk / SS, s = chunk % SS;
    const float* xp = x + (size_t)(b*TT + s*TPC) * DD + d;
    float sum = 0.f;
    #pragma unroll 8
    for (int t = 0; t < TPC; ++t) sum += xp[(size_t)t * DD];
    ws[PA_OFF + (size_t)chunk * DD + d] = sum;
}

// ---- Kernel B: fused per-batch centroids + batch centroid + scalars (1 block, 256 thr) ----
__global__ void kB(const float* __restrict__ beta, float* __restrict__ ws) {
    int tid = threadIdx.x, lane = tid & 63, wv = tid >> 6;
    float sgn0 = (lane == 0) ? -1.f : 1.f;
    const float4* pa = (const float4*)(ws + PA_OFF);
    float4 acc = {0.f, 0.f, 0.f, 0.f};
    for (int i = 0; i < 16; ++i) {
        int b = wv * 16 + i;
        float4 m = {0.f, 0.f, 0.f, 0.f};
        const float4* pp = pa + (size_t)b * SS * 64 + lane;
        #pragma unroll
        for (int s = 0; s < SS; ++s) {
            float4 t = pp[(size_t)s * 64];
            m.x += t.x; m.y += t.y; m.z += t.z; m.w += t.w;
        }
        const float inv_tt = 1.0f / TT;
        m.x *= inv_tt; m.y *= inv_tt; m.z *= inv_tt; m.w *= inv_tt;
        float p = sgn0 * m.x * m.x + m.y * m.y + m.z * m.z + m.w * m.w;
        #pragma unroll
        for (int o = 32; o; o >>= 1) p += __shfl_xor(p, o, 64);
        float inv = 1.0f / sqrtf(fmaxf(-p, 1e-8f));
        acc.x += m.x * inv; acc.y += m.y * inv; acc.z += m.z * inv; acc.w += m.w * inv;
    }
    __shared__ float4 sh4[4][64];
    sh4[wv][lane] = acc;
    __syncthreads();
    if (wv == 0) {
        float4 a;
        a.x = sh4[0][lane].x + sh4[1][lane].x + sh4[2][lane].x + sh4[3][lane].x;
        a.y = sh4[0][lane].y + sh4[1][lane].y + sh4[2][lane].y + sh4[3][lane].y;
        a.z = sh4[0][lane].z + sh4[1][lane].z + sh4[2][lane].z + sh4[3][lane].z;
        a.w = sh4[0][lane].w + sh4[1][lane].w + sh4[2][lane].w + sh4[3][lane].w;
        const float inv_bb = 1.0f / BB;
        a.x *= inv_bb; a.y *= inv_bb; a.z *= inv_bb; a.w *= inv_bb;
        float p = sgn0 * a.x * a.x + a.y * a.y + a.z * a.z + a.w * a.w;
        #pragma unroll
        for (int o = 32; o; o >>= 1) p += __shfl_xor(p, o, 64);
        float inv = 1.0f / sqrtf(fmaxf(-p, 1e-8f));
        float4 mean4; mean4.x = a.x * inv; mean4.y = a.y * inv; mean4.z = a.z * inv; mean4.w = a.w * inv;
        float4 b4 = ((const float4*)beta)[lane];
        float4 w4; w4.x = mean4.x + b4.x; w4.y = mean4.y + b4.y; w4.z = mean4.z + b4.z; w4.w = mean4.w + b4.w;
        // fused butterflies: mb = <mean,beta>_L, ww = <w,w>_L
        float mb = sgn0 * mean4.x * b4.x + mean4.y * b4.y + mean4.z * b4.z + mean4.w * b4.w;
        float wwp = sgn0 * w4.x * w4.x + w4.y * w4.y + w4.z * w4.z + w4.w * w4.w;
        #pragma unroll
        for (int o = 32; o; o >>= 1) { mb += __shfl_xor(mb, o, 64); wwp += __shfl_xor(wwp, o, 64); }
        ((float4*)(ws + MEAN_OFF))[lane] = mean4;
        if (lane == 0) {
            ws[SC_OFF + 1] = 1.0f / (1.0f - mb);
            ws[SC_OFF + 2] = mb;
            ws[SC_OFF + 3] = wwp;
            ws[SC_OFF + 4] = mean4.x;   // mean0
        }
    }
}

// ---- Kernel C: per-token xy=<mean,y>, by=<beta,y>, y0; d^2 partials (wave/token) ----
__global__ void kC(const float* __restrict__ x, const float* __restrict__ beta,
                   float* __restrict__ ws) {
    int tid = threadIdx.x, lane = tid & 63, wv = tid >> 6;
    int gw = blockIdx.x * 4 + wv;
    int nw = gridDim.x * 4;
    float4 m4 = ((const float4*)(ws + MEAN_OFF))[lane];
    float4 b4 = ((const float4*)beta)[lane];
    float sgn0 = (lane == 0) ? -1.f : 1.f;
    float lsum = 0.f;
    for (int tok = gw; tok < BT; tok += nw) {
        float4 x4 = ((const float4*)(x + (size_t)tok * DD))[lane];
        float pxy = sgn0 * m4.x * x4.x + m4.y * x4.y + m4.z * x4.z + m4.w * x4.w;
        float pby = sgn0 * b4.x * x4.x + b4.y * x4.y + b4.z * x4.z + b4.w * x4.w;
        #pragma unroll
        for (int o = 32; o; o >>= 1) {
            pxy += __shfl_xor(pxy, o, 64);
            pby += __shfl_xor(pby, o, 64);
        }
        if (lane == 0) {
            float4 sc; sc.x = pxy; sc.y = pby; sc.z = x4.x; sc.w = 0.f;
            ((float4*)(ws + SCAL_OFF))[tok] = sc;
        }
        float arg = fmaxf(-pxy, 1.0f + 1e-7f);
        float dd = acoshf(arg);
        lsum += fmaxf(dd * dd, 1e-8f);
    }
    __shared__ float sh[4];
    if (lane == 0) sh[wv] = lsum;
    __syncthreads();
    if (tid == 0) ws[DP_OFF + blockIdx.x] = sh[0] + sh[1] + sh[2] + sh[3];
}

// ---- Kernel S: per-token A,B,C scalars (var reduce folded in; 256 blocks x 256 thr) ----
__global__ void kS(const float* __restrict__ gamma, float* __restrict__ ws) {
    int tid = threadIdx.x;
    // fold the global variance reduction (redundant per block, deterministic)
    float s = 0.f;
    #pragma unroll
    for (int i = tid; i < 2048; i += 256) s += ws[DP_OFF + i];
    float tot = block_reduce_256(s);
    float var = sqrtf(tot / (float)BT);
    float scale = gamma[0] / (var + 1e-5f);

    float invden = ws[SC_OFF + 1];
    float mb     = ws[SC_OFF + 2];
    float ww     = ws[SC_OFF + 3];
    float mean0  = ws[SC_OFF + 4];

    int tok = blockIdx.x * 256 + tid;
    float4 sc = ((const float4*)(ws + SCAL_OFF))[tok];
    float xy = sc.x, by = sc.y, y0 = sc.z;

    float d   = acoshf(fmaxf(-xy, 1.0f + 1e-7f));
    float un2 = fmaxf(xy * xy - 1.0f, 1e-8f);
    float f1  = d * scale / sqrtf(un2);
    float u0  = y0 + xy * mean0;
    float en2 = f1 * f1 * (un2 + 2.0f * u0 * u0);     // Euclid ||v||^2
    float n   = sqrtf(en2);
    float factor = fminf(1.0f, 32.0f / fmaxf(n, 1e-8f));
    float ff1 = factor * f1;
    float bv  = ff1 * (by + xy * mb);                 // <beta, v_f>_L
    float coeff = bv * invden;
    float vn2 = ff1 * ff1 * un2 + 2.0f * coeff * bv + coeff * coeff * ww;
    float vn  = sqrtf(fmaxf(vn2, 1e-8f));
    float shv = sinhf(vn) / vn;
    float chv = coshf(vn);
    float4 abc;
    abc.x = shv * ff1;                 // A: multiplies y
    abc.y = shv * (ff1 * xy + coeff);  // B: multiplies mean
    abc.z = chv + shv * coeff;         // C: multiplies beta
    abc.w = 0.f;
    ((float4*)(ws + ABC_OFF))[tok] = abc;
}

// ---- Kernel E: pure streaming out = A*y + B*mean + C*beta (wave/token) ----
__global__ void kE(const float* __restrict__ x, const float* __restrict__ beta,
                   const float* __restrict__ ws, float* __restrict__ out) {
    int tid = threadIdx.x, lane = tid & 63, wv = tid >> 6;
    int tok = blockIdx.x * 4 + wv;
    float4 m4 = ((const float4*)(ws + MEAN_OFF))[lane];
    float4 b4 = ((const float4*)beta)[lane];
    float4 abc = ((const float4*)(ws + ABC_OFF))[tok];
    float A = abc.x, B = abc.y, C = abc.z;
    float4 x4 = ((const float4*)(x + (size_t)tok * DD))[lane];
    float4 o4;
    o4.x = A * x4.x + B * m4.x + C * b4.x;
    o4.y = A * x4.y + B * m4.y + C * b4.y;
    o4.z = A * x4.z + B * m4.z + C * b4.z;
    o4.w = A * x4.w + B * m4.w + C * b4.w;
    ((float4*)(out + (size_t)tok * DD))[lane] = o4;
}

extern "C" void kernel_launch(void* const* d_in, const int* in_sizes, int n_in,
                              void* d_out, int out_size, void* d_ws, size_t ws_size,
                              hipStream_t stream) {
    const float* x     = (const float*)d_in[0];
    const float* beta  = (const float*)d_in[1];
    const float* gamma = (const float*)d_in[2];
    float* out = (float*)d_out;
    float* ws  = (float*)d_ws;

    kA<<<BB*SS,  256, 0, stream>>>(x, ws);
    kB<<<1,      256, 0, stream>>>(beta, ws);
    kC<<<2048,   256, 0, stream>>>(x, beta, ws);
    kS<<<BT/256, 256, 0, stream>>>(gamma, ws);
    kE<<<BT/4,   256, 0, stream>>>(x, beta, ws, out);
}